// Round 5
// baseline (2863.675 us; speedup 1.0000x reference)
//
#include <hip/hip_runtime.h>
#include <hip/hip_bf16.h>
#include <stdint.h>

// Persistent LSTM: 256 WGs = 8 batch-groups (32 batches) x 32 hidden-slices
// (16 hid = 64 gate rows). W_hh/W_ih fragments live in REGISTERS all 512 steps.
// Per-step h exchange through d_ws (bf16 double buffer) using agent-scope
// atomics only (no fences, no cache writebacks/invalidates in the loop).

#define NB 256
#define NT 512
#define NF 130
#define NK 128
#define NH 512

typedef float f32x4 __attribute__((ext_vector_type(4)));
typedef float f32x2 __attribute__((ext_vector_type(2)));
typedef short bf16x8 __attribute__((ext_vector_type(8)));

__device__ __forceinline__ short bf1(float f) {
  union { float f; uint32_t u; } v; v.f = f;
  uint32_t r = (v.u + 0x7FFFu + ((v.u >> 16) & 1u)) >> 16;  // RNE
  return (short)r;
}

__device__ __forceinline__ bf16x8 cvt8(const float* p) {
  bf16x8 r;
#pragma unroll
  for (int i = 0; i < 4; ++i) {
    f32x2 t = *(const f32x2*)(p + 2 * i);   // 8B-aligned at every call site
    r[2 * i]     = bf1(t[0]);
    r[2 * i + 1] = bf1(t[1]);
  }
  return r;
}

__device__ __forceinline__ float fsig(float x) {
  return __builtin_amdgcn_rcpf(1.0f + __builtin_amdgcn_exp2f(-1.44269504f * x));
}
__device__ __forceinline__ float ftanh(float x) {
  return 2.0f * __builtin_amdgcn_rcpf(1.0f + __builtin_amdgcn_exp2f(-2.88539008f * x)) - 1.0f;
}

__global__ __launch_bounds__(256, 2) void lstm_pers(
    const float* __restrict__ xin, const int* __restrict__ lens,
    const float* __restrict__ h0, const float* __restrict__ c0,
    const float* __restrict__ Wih, const float* __restrict__ Whh,
    const float* __restrict__ bih, const float* __restrict__ bhh,
    float* __restrict__ out, unsigned* __restrict__ cnt,
    unsigned short* __restrict__ hbuf /* [2][NB][NH] bf16 bits */) {
  const int blk = blockIdx.x;
  const int g  = blk & 7;    // batch group (XCD-affine under round-robin)
  const int s  = blk >> 3;   // hidden slice 0..31
  const int hb = s << 4;     // hidden base (16 per WG)
  const int gb = g << 5;     // batch base (32 per group)
  const int tid = threadIdx.x;
  const int w  = tid >> 6;   // wave 0..3
  const int l  = tid & 63;
  const int n  = w & 1;      // batch half (N-tile)
  const int kh = w >> 1;     // K half
  const int q  = l >> 4;
  const int col = l & 15;
  const int bidx = gb + (n << 4) + col;   // this lane's batch (B-frag col / C col)

  // A-frag: lane holds A[row=l&15][k=8*(l>>4)+j]. Row-in-tile rm = 4*qh+sg so
  // the C/D layout (row = 4*(l>>4)+reg) hands each lane {i,f,g,o} of ONE hid.
  const int rm = l & 15;
  const int qh = rm >> 2;
  const int sg = rm & 3;

  // ---- load weight fragments into registers (once) ----
  bf16x8 whh[4][8];  // [m-tile][k-tile of 32], k = kh*256 + kt*32 + 8q
  bf16x8 wih[4][2];  // [m-tile][k-tile], feat = kh*64 + kt*32 + 8q
#pragma unroll
  for (int m = 0; m < 4; ++m) {
    const int grow = sg * NH + hb + (m << 2) + qh;  // global gate row
    const float* pw = Whh + (size_t)grow * NH + kh * 256 + q * 8;
#pragma unroll
    for (int kt = 0; kt < 8; ++kt) whh[m][kt] = cvt8(pw + kt * 32);
    const float* pi = Wih + (size_t)grow * NK + kh * 64 + q * 8;
#pragma unroll
    for (int kt = 0; kt < 2; ++kt) wih[m][kt] = cvt8(pi + kt * 32);
  }

  f32x4 bias[4];
  float cst[4];
  int blen = -1;
  if (kh == 0) {  // owner waves hold c, biases, len; publish h0 (agent scope)
    blen = lens[bidx];
#pragma unroll
    for (int m = 0; m < 4; ++m) {
      const int hid = hb + (m << 2) + q;
#pragma unroll
      for (int p = 0; p < 4; ++p)
        bias[m][p] = bih[p * NH + hid] + bhh[p * NH + hid];
      cst[m] = c0[(size_t)bidx * NH + hid];
      __hip_atomic_store(&hbuf[(size_t)bidx * NH + hid],
                         (unsigned short)bf1(h0[(size_t)bidx * NH + hid]),
                         __ATOMIC_RELAXED, __HIP_MEMORY_SCOPE_AGENT);
    }
  }

  __shared__ __align__(16) float mrg[2][64][20];  // K-half partials, padded

  __syncthreads();  // drains vmcnt(0): h0 stores visible at coherence point
  if (tid == 0)
    __hip_atomic_fetch_add(cnt + g * 32, 1u, __ATOMIC_RELAXED, __HIP_MEMORY_SCOPE_AGENT);

  const unsigned short* hsb = hbuf + (size_t)bidx * NH + kh * 256 + q * 8;
  int dead = 0;

  for (int t = 0; t < NT; ++t) {
    // ---- x-projection (h-independent) issued in the sync shadow ----
    f32x4 acc[4];
    const f32x4 zero = {0.f, 0.f, 0.f, 0.f};
#pragma unroll
    for (int m = 0; m < 4; ++m) acc[m] = zero;
    {
      const float* px = xin + (size_t)bidx * (NT * NF) + (size_t)t * NF + kh * 64 + q * 8;
#pragma unroll
      for (int kt = 0; kt < 2; ++kt) {
        bf16x8 xf = cvt8(px + kt * 32);
#pragma unroll
        for (int m = 0; m < 4; ++m)
          acc[m] = __builtin_amdgcn_mfma_f32_16x16x32_bf16(wih[m][kt], xf, acc[m], 0, 0, 0);
      }
    }
    // ---- per-wave wait: all 32 WGs of this group published h(t) ----
    if (l == 0 && !dead) {
      const unsigned tgt = 32u * (unsigned)(t + 1);
      long spins = 0;
      while (__hip_atomic_load(cnt + g * 32, __ATOMIC_RELAXED, __HIP_MEMORY_SCOPE_AGENT) < tgt) {
        __builtin_amdgcn_s_sleep(1);
        if (++spins > (1L << 19)) { dead = 1; break; }  // bail, don't hang
      }
    }
    asm volatile("" ::: "memory");  // keep h loads below the spin
    // ---- h-projection: agent-scope 8B loads (coherent, no invalidates) ----
    const unsigned short* hs = hsb + ((size_t)(t & 1)) * (NB * NH);
#pragma unroll
    for (int kt = 0; kt < 8; ++kt) {
      union { unsigned long long u[2]; bf16x8 v; } hu;
      hu.u[0] = __hip_atomic_load((const unsigned long long*)(hs + kt * 32),
                                  __ATOMIC_RELAXED, __HIP_MEMORY_SCOPE_AGENT);
      hu.u[1] = __hip_atomic_load((const unsigned long long*)(hs + kt * 32 + 4),
                                  __ATOMIC_RELAXED, __HIP_MEMORY_SCOPE_AGENT);
#pragma unroll
      for (int m = 0; m < 4; ++m)
        acc[m] = __builtin_amdgcn_mfma_f32_16x16x32_bf16(whh[m][kt], hu.v, acc[m], 0, 0, 0);
    }
    // ---- merge K halves across wave pairs ----
    if (kh == 1) {
#pragma unroll
      for (int m = 0; m < 4; ++m)
        *(f32x4*)(&mrg[n][l][m * 4]) = acc[m];
    }
    __syncthreads();
    if (kh == 0) {
      unsigned short* hw = hbuf + ((size_t)((t + 1) & 1)) * (NB * NH) + (size_t)bidx * NH;
#pragma unroll
      for (int m = 0; m < 4; ++m) {
        f32x4 gv = acc[m] + *(const f32x4*)(&mrg[n][l][m * 4]) + bias[m];
        float ig = fsig(gv[0]);
        float fg = fsig(gv[1]);
        float gg = ftanh(gv[2]);
        float og = fsig(gv[3]);
        float cc = fg * cst[m] + ig * gg;
        cst[m] = cc;
        float hh = og * ftanh(cc);
        const int hid = hb + (m << 2) + q;
        __hip_atomic_store(&hw[hid], (unsigned short)bf1(hh),
                           __ATOMIC_RELAXED, __HIP_MEMORY_SCOPE_AGENT);
        if (t == blen - 1) out[(size_t)bidx * NH + hid] = hh;
      }
    }
    __syncthreads();  // all waves' reads done + stores drained (vmcnt 0)
    if (tid == 0)
      __hip_atomic_fetch_add(cnt + g * 32, 1u, __ATOMIC_RELAXED, __HIP_MEMORY_SCOPE_AGENT);
  }
}

extern "C" void kernel_launch(void* const* d_in, const int* in_sizes, int n_in,
                              void* d_out, int out_size, void* d_ws, size_t ws_size,
                              hipStream_t stream) {
  const float* xin  = (const float*)d_in[0];
  const int*   lens = (const int*)d_in[1];
  const float* h0   = (const float*)d_in[2];
  const float* c0   = (const float*)d_in[3];
  const float* Wih  = (const float*)d_in[4];
  const float* Whh  = (const float*)d_in[5];
  const float* bih  = (const float*)d_in[6];
  const float* bhh  = (const float*)d_in[7];
  float* out = (float*)d_out;

  unsigned* cnt = (unsigned*)d_ws;                              // 8 counters, 128B apart
  unsigned short* hbuf = (unsigned short*)((char*)d_ws + 4096); // 2*256*512 bf16 = 512KB

  hipMemsetAsync(d_ws, 0, 4096, stream);  // zero counters (ws is re-poisoned)
  lstm_pers<<<dim3(256), dim3(256), 0, stream>>>(xin, lens, h0, c0, Wih, Whh, bih, bhh,
                                                 out, cnt, hbuf);
}